// Round 8
// baseline (149.786 us; speedup 1.0000x reference)
//
#include <hip/hip_runtime.h>
#include <cstdint>
#include <cstddef>

#define N_NODES 50000
#define N_EDGES 800000
#define IN_CH   64
#define OC      128   // HEADS*OUT_CH
#define HEADS   4
#define CH      32    // OUT_CH

#define NB      391        // dst buckets: 128 nodes each (d>>7)
#define BCAP    2560       // per-bucket capacity (mean 2046, +11 sigma)
#define EPB     4096       // edges per histA block (256 threads x 16)
#define HIST_BLOCKS ((N_EDGES + EPB - 1) / EPB)   // 196

typedef __attribute__((ext_vector_type(8))) short short8;   // 8 bf16 (4 VGPRs)
typedef __attribute__((ext_vector_type(4))) float f32x4;

static inline int ceil_div(int a, int b){ return (a + b - 1) / b; }

__device__ __forceinline__ float lrelu(float x){ return fmaxf(x, 0.2f * x); }

__device__ __forceinline__ unsigned pack_bf16(float x, float y){
  unsigned ux = __float_as_uint(x), uy = __float_as_uint(y);
  ux += 0x7FFFu + ((ux >> 16) & 1u);
  uy += 0x7FFFu + ((uy >> 16) & 1u);
  return (ux >> 16) | (uy & 0xFFFF0000u);   // low16 = x, high16 = y
}

// ---- K1: cnt_nt atomics + block-aggregated bucket scatter ----
// entry = (b<<23) | (doff<<16) | src   (b<512, doff<128, src<65536)
__global__ __launch_bounds__(256) void k_histA(const int* __restrict__ ei,
                                               const int* __restrict__ et,
                                               unsigned* __restrict__ cnt_nt,
                                               int* __restrict__ btail,
                                               unsigned* __restrict__ bbuf){
  __shared__ int cnt[NB + 1];
  __shared__ int pos[NB + 1];
  int tid = threadIdx.x;
  for (int i = tid; i <= NB; i += 256){ cnt[i] = 0; }
  __syncthreads();

  int e0 = blockIdx.x * EPB;
  unsigned ent[16];
  #pragma unroll
  for (int j = 0; j < 16; ++j){
    int e = e0 + j * 256 + tid;
    ent[j] = 0xFFFFFFFFu;
    if (e < N_EDGES){
      int s = ei[e], d = ei[N_EDGES + e], t = et[e];
      atomicAdd(&cnt_nt[(size_t)s * 16 + (t >> 2)], 1u << (8 * (t & 3)));
      int b = d >> 7;
      ent[j] = ((unsigned)b << 23) | ((unsigned)(d & 127) << 16) | (unsigned)s;
      atomicAdd(&cnt[b], 1);
    }
  }
  __syncthreads();
  for (int i = tid; i < NB; i += 256){
    int c = cnt[i];
    pos[i] = c ? atomicAdd(&btail[i], c) : 0;
  }
  __syncthreads();
  #pragma unroll
  for (int j = 0; j < 16; ++j){
    if (ent[j] != 0xFFFFFFFFu){
      int b = ent[j] >> 23;
      int p = atomicAdd(&pos[b], 1);
      if (p < BCAP) bbuf[(size_t)b * BCAP + p] = ent[j];
    }
  }
}

// ---- merged pass B: bucket -> row_dst + u16 lst (count+scan+write, one kernel) ----
__global__ __launch_bounds__(256) void k_passB(const unsigned* __restrict__ bbuf,
                                               const int* __restrict__ btail,
                                               int* __restrict__ row_dst,
                                               unsigned short* __restrict__ lst){
  __shared__ unsigned ub[BCAP];      // 10 KB bucket stage
  __shared__ int cnt[128], sc[128], cur[128];
  __shared__ int sbase;
  int b = blockIdx.x, tid = threadIdx.x;
  int d0 = b << 7;
  int nn = min(128, N_NODES - d0);
  int cnt_b = min(btail[b], BCAP);

  // bucket base = sum of previous bucket sizes (btail is 1.5KB, L2-hot)
  {
    int part = 0;
    for (int q = tid; q < b; q += 256) part += min(btail[q], BCAP);
    // wave+block reduce via LDS
    __shared__ int red[256];
    red[tid] = part; __syncthreads();
    for (int off = 128; off > 0; off >>= 1){
      if (tid < off) red[tid] += red[tid + off];
      __syncthreads();
    }
    if (tid == 0) sbase = red[0];
    __syncthreads();
  }
  int base0 = sbase;

  if (tid < 128) cnt[tid] = 0;
  __syncthreads();
  for (int i = tid; i < cnt_b; i += 256){
    unsigned e = bbuf[(size_t)b * BCAP + i];
    ub[i] = e;
    atomicAdd(&cnt[(e >> 16) & 127], 1);
  }
  __syncthreads();
  // exclusive scan of cnt[128]
  if (tid < 128) sc[tid] = cnt[tid];
  __syncthreads();
  for (int off = 1; off < 128; off <<= 1){
    int t = (tid < 128 && tid >= off) ? sc[tid - off] : 0;
    __syncthreads();
    if (tid < 128) sc[tid] += t;
    __syncthreads();
  }
  if (tid < nn){
    int ex = sc[tid] - cnt[tid];
    cur[tid] = ex;
    row_dst[d0 + tid] = base0 + ex;
  }
  if (b == NB - 1 && tid == 0) row_dst[N_NODES] = base0 + cnt_b;
  __syncthreads();
  for (int i = tid; i < cnt_b; i += 256){
    unsigned e = ub[i];
    int p = atomicAdd(&cur[(e >> 16) & 127], 1);
    lst[base0 + p] = (unsigned short)(e & 0xFFFFu);
  }
}

// ---- k_prep: B = [W ; pe@W] (128x128) -> bf16, packed in MFMA B-frag order ----
__global__ __launch_bounds__(256) void k_prep(const float* __restrict__ pe,
                                              const float* __restrict__ W,
                                              unsigned* __restrict__ Bh){
  __shared__ float sPe[64 * 64];    // 16 KB
  __shared__ float sPeW[64 * 128];  // 32 KB
  int tid = threadIdx.x;
  for (int i = tid; i < 64 * 64 / 4; i += 256)
    ((float4*)sPe)[i] = ((const float4*)pe)[i];
  __syncthreads();
  int c = tid & 127, rb = tid >> 7;
  for (int k = 0; k < 32; ++k){
    int t = rb + 2 * k;
    float a = 0.f;
    #pragma unroll
    for (int i = 0; i < 64; ++i) a += sPe[t * 64 + i] * W[i * 128 + c];
    sPeW[t * 128 + c] = a;
  }
  __syncthreads();
  for (int o = tid; o < 8192; o += 256){
    int j2 = o & 3, l = (o >> 2) & 63, kk = (o >> 8) & 3, nt = o >> 10;
    int k = kk * 32 + (l >> 4) * 8 + 2 * j2;
    int n = nt * 16 + (l & 15);
    float v0 = (k     < 64) ? W[k * 128 + n]       : sPeW[(k - 64) * 128 + n];
    float v1 = (k + 1 < 64) ? W[(k + 1) * 128 + n] : sPeW[(k + 1 - 64) * 128 + n];
    Bh[o] = pack_bf16(v0, v1);
  }
}

// ---- MFMA GEMM: xl = [x | cnt] @ [W ; peW], 64 rows/block, 4 waves ----
#define GEMM_ROWS 64
__global__ __launch_bounds__(256) void k_gemm_mfma(const float* __restrict__ x,
                                                   const unsigned* __restrict__ cnt_nt,
                                                   const unsigned* __restrict__ Bh,
                                                   const float* __restrict__ att_s,
                                                   const float* __restrict__ att_d,
                                                   float* __restrict__ a_src,
                                                   float* __restrict__ a_dst,
                                                   unsigned* __restrict__ xh){
  __shared__ unsigned sA[4096];   // 64 rows x 128 k bf16, XOR-swizzled, 16 KB
  __shared__ unsigned sB[8192];   // frag-packed B, 32 KB
  int tid = threadIdx.x;
  int row0 = blockIdx.x * GEMM_ROWS;

  {
    const uint4* srcp = (const uint4*)Bh;
    uint4* dstp = (uint4*)sB;
    #pragma unroll
    for (int i = 0; i < 8; ++i) dstp[tid + i * 256] = srcp[tid + i * 256];
  }
  {
    int r = tid >> 2, q = tid & 3;
    int n = row0 + r;
    unsigned swz = (unsigned)((r & 7) << 4);
    float4 xv[4];
    if (n < N_NODES){
      const float4* xr = (const float4*)(x + (size_t)n * 64);
      #pragma unroll
      for (int i = 0; i < 4; ++i) xv[i] = xr[q * 4 + i];
    } else {
      #pragma unroll
      for (int i = 0; i < 4; ++i) xv[i] = make_float4(0.f, 0.f, 0.f, 0.f);
    }
    unsigned pk[8];
    #pragma unroll
    for (int i = 0; i < 4; ++i){
      pk[2 * i]     = pack_bf16(xv[i].x, xv[i].y);
      pk[2 * i + 1] = pack_bf16(xv[i].z, xv[i].w);
    }
    unsigned b0 = (unsigned)(r * 256 + q * 32);
    *(uint4*)(sA + (((b0)      ^ swz) >> 2)) = make_uint4(pk[0], pk[1], pk[2], pk[3]);
    *(uint4*)(sA + (((b0 + 16) ^ swz) >> 2)) = make_uint4(pk[4], pk[5], pk[6], pk[7]);
    unsigned cw[4];
    if (n < N_NODES){
      uint4 cv = ((const uint4*)(cnt_nt + (size_t)n * 16))[q];
      cw[0] = cv.x; cw[1] = cv.y; cw[2] = cv.z; cw[3] = cv.w;
    } else { cw[0] = cw[1] = cw[2] = cw[3] = 0; }
    unsigned pc[8];
    #pragma unroll
    for (int i = 0; i < 4; ++i){
      unsigned v = cw[i];
      pc[2 * i]     = pack_bf16((float)(v & 0xFFu), (float)((v >> 8) & 0xFFu));
      pc[2 * i + 1] = pack_bf16((float)((v >> 16) & 0xFFu), (float)(v >> 24));
    }
    unsigned b1 = (unsigned)(r * 256 + 128 + q * 32);
    *(uint4*)(sA + (((b1)      ^ swz) >> 2)) = make_uint4(pc[0], pc[1], pc[2], pc[3]);
    *(uint4*)(sA + (((b1 + 16) ^ swz) >> 2)) = make_uint4(pc[4], pc[5], pc[6], pc[7]);
  }
  __syncthreads();

  int wid = tid >> 6, l = tid & 63;
  int c15 = l & 15, kq = l >> 4;
  int arow = wid * 16 + c15;
  f32x4 acc[8];
  #pragma unroll
  for (int nt = 0; nt < 8; ++nt) acc[nt] = (f32x4){0.f, 0.f, 0.f, 0.f};

  #pragma unroll
  for (int kk = 0; kk < 4; ++kk){
    unsigned abyte = (unsigned)(arow * 256 + kk * 64 + kq * 16);
    abyte ^= (unsigned)((arow & 7) << 4);
    short8 af = *(const short8*)((const char*)sA + abyte);
    #pragma unroll
    for (int nt = 0; nt < 8; ++nt){
      short8 bf = *(const short8*)(sB + (size_t)((nt * 4 + kk) * 64 + l) * 4);
      acc[nt] = __builtin_amdgcn_mfma_f32_16x16x32_bf16(af, bf, acc[nt], 0, 0, 0);
    }
  }

  float asv[8], adv[8];
  #pragma unroll
  for (int nt = 0; nt < 8; ++nt){
    asv[nt] = att_s[nt * 16 + c15];
    adv[nt] = att_d[nt * 16 + c15];
  }
  #pragma unroll
  for (int r = 0; r < 4; ++r){
    int row = row0 + wid * 16 + kq * 4 + r;
    bool valid = row < N_NODES;
    #pragma unroll
    for (int h = 0; h < 4; ++h){
      float ps = acc[2 * h][r] * asv[2 * h] + acc[2 * h + 1][r] * asv[2 * h + 1];
      float pd = acc[2 * h][r] * adv[2 * h] + acc[2 * h + 1][r] * adv[2 * h + 1];
      #pragma unroll
      for (int m = 1; m < 16; m <<= 1){
        ps += __shfl_xor(ps, m);
        pd += __shfl_xor(pd, m);
      }
      if (valid && c15 == 0){
        a_src[row * 4 + h] = ps;
        a_dst[row * 4 + h] = pd;
      }
    }
    #pragma unroll
    for (int nt = 0; nt < 8; ++nt){
      float own = acc[nt][r];
      float nb = __shfl_xor(own, 1);
      if (valid && !(c15 & 1))
        xh[(size_t)row * 64 + nt * 8 + (c15 >> 1)] = pack_bf16(own, nb);
    }
  }
}

// ---- fused aggregate: wave-parallel exp precompute + weighted sum + bias/ELU ----
// one wave per node; lane l owns channels (2l,2l+1); head h = l>>4.
__global__ __launch_bounds__(64) void k_aggregate(const int* __restrict__ row_dst,
                                                  const unsigned short* __restrict__ lst,
                                                  const float* __restrict__ a_src,
                                                  const float* __restrict__ a_dst,
                                                  const unsigned* __restrict__ xh,
                                                  const float* __restrict__ bias,
                                                  float* __restrict__ out){
  int n = blockIdx.x;
  int l = threadIdx.x;
  int h = l >> 4;
  int lh = l & 15;       // lane within head group
  int hb = l & 48;       // head-group base lane
  float ad = a_dst[n * 4 + h];

  // self loop
  float wself = __expf(lrelu(a_src[n * 4 + h] + ad));
  unsigned uv = xh[(size_t)n * 64 + l];
  float lp = (lh == 0) ? wself : 0.f;   // distributed lsum partial
  float accx = wself * __uint_as_float(uv << 16);
  float accy = wself * __uint_as_float(uv & 0xFFFF0000u);

  int k0 = row_dst[n], k1 = row_dst[n + 1];
  for (int kb = k0; kb < k1; kb += 64){
    int nk = k1 - kb; nk = nk < 64 ? nk : 64;
    int idx = kb + l;
    int sj = (int)lst[idx < k1 ? idx : k1 - 1];   // coalesced u16 batch

    // phase W: lane computes weight of edge er=16r+lh for its head (1 exp/lane/round)
    float w[4];
    #pragma unroll
    for (int r = 0; r < 4; ++r){
      int er = r * 16 + lh;
      int s = __shfl(sj, er);
      float ww = __expf(lrelu(a_src[s * 4 + h] + ad));
      w[r] = (er < nk) ? ww : 0.f;
      lp += w[r];
    }
    // phase ACC: gather xh rows, weights via shfl (static w[r] index)
    #pragma unroll
    for (int r = 0; r < 4; ++r){
      int jbase = r * 16;
      if (jbase >= nk) break;
      float wr = w[r];
      int jend = nk - jbase; jend = jend < 16 ? jend : 16;
      for (int j2 = 0; j2 < jend; ++j2){
        int s = __shfl(sj, jbase + j2);
        unsigned u = xh[(size_t)s * 64 + l];
        float wj = __shfl(wr, hb | j2);
        accx = fmaf(wj, __uint_as_float(u << 16), accx);
        accy = fmaf(wj, __uint_as_float(u & 0xFFFF0000u), accy);
      }
    }
  }
  // reduce lsum over the 16-lane head group
  float lsum = lp;
  #pragma unroll
  for (int m = 1; m < 16; m <<= 1) lsum += __shfl_xor(lsum, m);

  float2 b = ((const float2*)bias)[l];
  float r0 = accx / lsum + b.x;
  float r1 = accy / lsum + b.y;
  float2 o;
  o.x = r0 > 0.f ? r0 : expm1f(r0);
  o.y = r1 > 0.f ? r1 : expm1f(r1);
  ((float2*)out)[(size_t)n * 64 + l] = o;
}

extern "C" void kernel_launch(void* const* d_in, const int* in_sizes, int n_in,
                              void* d_out, int out_size, void* d_ws, size_t ws_size,
                              hipStream_t stream){
  const float* x     = (const float*)d_in[0];
  const int*   ei    = (const int*)d_in[1];   // [2, E]
  const int*   et    = (const int*)d_in[2];   // [E]
  const float* pe    = (const float*)d_in[3];
  const float* W     = (const float*)d_in[4];
  const float* att_s = (const float*)d_in[5];
  const float* att_d = (const float*)d_in[6];
  const float* bias  = (const float*)d_in[7];
  float* out = (float*)d_out;

  // workspace carve-up (4-byte units). [cnt_nt | btail] contiguous -> one memset.
  unsigned* cnt_nt  = (unsigned*)d_ws;                             // N*16 (u8 packed)
  int*      btail   = (int*)(cnt_nt + (size_t)N_NODES * 16);       // NB (pad 512)
  int*      row_dst = btail + 512;                                 // N+1 (pad 8)
  unsigned* Bh      = (unsigned*)(row_dst + N_NODES + 8);          // 8192
  float*    a_src   = (float*)(Bh + 8192);                         // N*4
  float*    a_dst   = a_src + (size_t)N_NODES * 4;                 // N*4
  unsigned* xh      = (unsigned*)(a_dst + (size_t)N_NODES * 4);    // N*64 (bf16x2)
  unsigned* bbuf    = xh + (size_t)N_NODES * 64;                   // NB*BCAP
  unsigned short* lst = (unsigned short*)(bbuf + (size_t)NB * BCAP); // E u16

  const int B = 256;

  hipMemsetAsync(cnt_nt, 0, ((size_t)N_NODES * 16 + 512) * sizeof(int), stream);
  k_prep<<<1, B, 0, stream>>>(pe, W, Bh);
  k_histA<<<HIST_BLOCKS, B, 0, stream>>>(ei, et, cnt_nt, btail, bbuf);
  k_passB<<<NB, B, 0, stream>>>(bbuf, btail, row_dst, lst);
  k_gemm_mfma<<<ceil_div(N_NODES, GEMM_ROWS), B, 0, stream>>>(x, cnt_nt, Bh,
                                                              att_s, att_d,
                                                              a_src, a_dst, xh);
  k_aggregate<<<N_NODES, 64, 0, stream>>>(row_dst, lst, a_src, a_dst, xh, bias, out);
}

// Round 9
// 113.360 us; speedup vs baseline: 1.3213x; 1.3213x over previous
//
#include <hip/hip_runtime.h>
#include <cstdint>
#include <cstddef>

#define N_NODES 50000
#define N_EDGES 800000
#define IN_CH   64
#define OC      128   // HEADS*OUT_CH
#define HEADS   4
#define CH      32    // OUT_CH

#define NB      391        // buckets: 128 nodes each (n>>7); one set for dst, one for src
#define BCAP    2560       // per-bucket capacity (mean 2046, +11 sigma)
#define EPB     2048       // edges per histA block (256 threads x 8)
#define HIST_BLOCKS ((N_EDGES + EPB - 1) / EPB)   // 391

typedef __attribute__((ext_vector_type(8))) short short8;   // 8 bf16 (4 VGPRs)
typedef __attribute__((ext_vector_type(4))) float f32x4;

static inline int ceil_div(int a, int b){ return (a + b - 1) / b; }

__device__ __forceinline__ float lrelu(float x){ return fmaxf(x, 0.2f * x); }

__device__ __forceinline__ unsigned pack_bf16(float x, float y){
  unsigned ux = __float_as_uint(x), uy = __float_as_uint(y);
  ux += 0x7FFFu + ((ux >> 16) & 1u);
  uy += 0x7FFFu + ((uy >> 16) & 1u);
  return (ux >> 16) | (uy & 0xFFFF0000u);   // low16 = x, high16 = y
}

// ---- K1: block-aggregated scatter into BOTH bucket structures ----
// dst entry: (bd<<23)|(doff<<16)|src ; src entry: (bs<<23)|(soff<<16)|type
__global__ __launch_bounds__(256) void k_histA(const int* __restrict__ ei,
                                               const int* __restrict__ et,
                                               int* __restrict__ btail,
                                               unsigned* __restrict__ bbuf){
  __shared__ int cnt[2 * NB + 2];
  __shared__ int pos[2 * NB + 2];
  int tid = threadIdx.x;
  for (int i = tid; i < 2 * NB + 2; i += 256) cnt[i] = 0;
  __syncthreads();

  int e0 = blockIdx.x * EPB;
  unsigned ed[8], es[8];
  #pragma unroll
  for (int j = 0; j < 8; ++j){
    int e = e0 + j * 256 + tid;
    ed[j] = 0xFFFFFFFFu; es[j] = 0xFFFFFFFFu;
    if (e < N_EDGES){
      int s = ei[e], d = ei[N_EDGES + e], t = et[e];
      ed[j] = ((unsigned)(d >> 7) << 23) | ((unsigned)(d & 127) << 16) | (unsigned)s;
      es[j] = ((unsigned)(s >> 7) << 23) | ((unsigned)(s & 127) << 16) | (unsigned)t;
      atomicAdd(&cnt[ed[j] >> 23], 1);
      atomicAdd(&cnt[NB + (es[j] >> 23)], 1);
    }
  }
  __syncthreads();
  for (int i = tid; i < 2 * NB; i += 256){
    int c = cnt[i];
    pos[i] = c ? atomicAdd(&btail[i], c) : 0;
  }
  __syncthreads();
  #pragma unroll
  for (int j = 0; j < 8; ++j){
    if (ed[j] != 0xFFFFFFFFu){
      int b = ed[j] >> 23;
      int p = atomicAdd(&pos[b], 1);
      if (p < BCAP) bbuf[(size_t)b * BCAP + p] = ed[j];
      int b2 = NB + (es[j] >> 23);
      int p2 = atomicAdd(&pos[b2], 1);
      if (p2 < BCAP) bbuf[(size_t)b2 * BCAP + p2] = es[j];
    }
  }
}

// ---- merged pass B ----
// blocks [0,NB): dst buckets -> row_dst + u16 lst
// blocks [NB,2NB): src buckets -> cb (bf16-pair (node,type) count table, GEMM-ready)
__global__ __launch_bounds__(256) void k_passB(const unsigned* __restrict__ bbuf,
                                               const int* __restrict__ btail,
                                               int* __restrict__ row_dst,
                                               unsigned short* __restrict__ lst,
                                               unsigned* __restrict__ cb){
  int g = blockIdx.x, tid = threadIdx.x;
  if (g < NB){
    __shared__ int cnt[128], sc[128], cur[128], red[256];
    __shared__ int sbase;
    int d0 = g << 7;
    int nn = min(128, N_NODES - d0);
    int cnt_b = min(btail[g], BCAP);
    // bucket base = sum of previous dst-bucket sizes
    int part = 0;
    for (int q = tid; q < g; q += 256) part += min(btail[q], BCAP);
    red[tid] = part; __syncthreads();
    for (int off = 128; off > 0; off >>= 1){
      if (tid < off) red[tid] += red[tid + off];
      __syncthreads();
    }
    if (tid == 0) sbase = red[0];
    if (tid < 128) cnt[tid] = 0;
    __syncthreads();
    int base0 = sbase;
    for (int i = tid; i < cnt_b; i += 256)
      atomicAdd(&cnt[(bbuf[(size_t)g * BCAP + i] >> 16) & 127], 1);
    __syncthreads();
    if (tid < 128) sc[tid] = cnt[tid];
    __syncthreads();
    for (int off = 1; off < 128; off <<= 1){
      int t = (tid < 128 && tid >= off) ? sc[tid - off] : 0;
      __syncthreads();
      if (tid < 128) sc[tid] += t;
      __syncthreads();
    }
    if (tid < nn){
      int ex = sc[tid] - cnt[tid];
      cur[tid] = ex;
      row_dst[d0 + tid] = base0 + ex;
    }
    if (g == NB - 1 && tid == 0) row_dst[N_NODES] = base0 + cnt_b;
    __syncthreads();
    for (int i = tid; i < cnt_b; i += 256){
      unsigned e = bbuf[(size_t)g * BCAP + i];
      int p = atomicAdd(&cur[(e >> 16) & 127], 1);
      lst[base0 + p] = (unsigned short)(e & 0xFFFFu);
    }
  } else {
    __shared__ unsigned hist[128 * 16];   // u8-packed per-node type counts, 8 KB
    int n0 = (g - NB) << 7;
    int nn = min(128, N_NODES - n0);
    for (int i = tid; i < 2048; i += 256) hist[i] = 0;
    __syncthreads();
    int cnt_b = min(btail[g], BCAP);
    for (int i = tid; i < cnt_b; i += 256){
      unsigned e = bbuf[(size_t)g * BCAP + i];
      unsigned t = e & 63u;
      atomicAdd(&hist[((e >> 16) & 127) * 16 + (t >> 2)], 1u << (8 * (t & 3)));
    }
    __syncthreads();
    for (int o = tid; o < 4096; o += 256){
      int i = o >> 5, j = o & 31;
      if (i < nn){
        unsigned w = hist[i * 16 + (j >> 1)];
        unsigned sh = 16 * (j & 1);
        cb[(size_t)(n0 + i) * 32 + j] =
          pack_bf16((float)((w >> sh) & 0xFFu), (float)((w >> (sh + 8)) & 0xFFu));
      }
    }
  }
}

// ---- k_prep (8 blocks): Bh = bf16 frag-packed [W ; pe@W], 16-col slice per block ----
__global__ __launch_bounds__(256) void k_prep(const float* __restrict__ pe,
                                              const float* __restrict__ W,
                                              unsigned* __restrict__ Bh){
  __shared__ float sPe[64 * 64];    // 16 KB
  __shared__ float sW64[64 * 16];   // [k][j], 4 KB
  __shared__ float sPeW[64 * 16];   // [t][j], 4 KB
  int tid = threadIdx.x;
  int nt = blockIdx.x;
  int n0 = nt * 16;
  for (int i = tid; i < 1024; i += 256)
    ((float4*)sPe)[i] = ((const float4*)pe)[i];
  for (int i = tid; i < 1024; i += 256){
    int k = i >> 4, j = i & 15;
    sW64[i] = W[k * 128 + n0 + j];
  }
  __syncthreads();
  for (int i = tid; i < 1024; i += 256){
    int t = i >> 4, j = i & 15;
    float a = 0.f;
    #pragma unroll
    for (int k = 0; k < 64; ++k) a += sPe[t * 64 + k] * sW64[k * 16 + j];
    sPeW[i] = a;
  }
  __syncthreads();
  for (int m = tid; m < 1024; m += 256){
    int j2 = m & 3, l = (m >> 2) & 63, kk = m >> 8;
    int k = kk * 32 + (l >> 4) * 8 + 2 * j2;   // even, pairs never straddle 64
    int jl = l & 15;
    float v0, v1;
    if (k < 64){ v0 = sW64[k * 16 + jl]; v1 = sW64[(k + 1) * 16 + jl]; }
    else       { v0 = sPeW[(k - 64) * 16 + jl]; v1 = sPeW[(k - 63) * 16 + jl]; }
    Bh[nt * 1024 + m] = pack_bf16(v0, v1);
  }
}

// ---- MFMA GEMM: xl = [x | cnt] @ [W ; peW], 64 rows/block, 4 waves ----
#define GEMM_ROWS 64
__global__ __launch_bounds__(256) void k_gemm_mfma(const float* __restrict__ x,
                                                   const unsigned* __restrict__ cb,
                                                   const unsigned* __restrict__ Bh,
                                                   const float* __restrict__ att_s,
                                                   const float* __restrict__ att_d,
                                                   float* __restrict__ a_src,
                                                   float* __restrict__ a_dst,
                                                   unsigned* __restrict__ xh){
  __shared__ unsigned sA[4096];   // 64 rows x 128 k bf16, XOR-swizzled, 16 KB
  __shared__ unsigned sB[8192];   // frag-packed B, 32 KB
  int tid = threadIdx.x;
  int row0 = blockIdx.x * GEMM_ROWS;

  {
    const uint4* srcp = (const uint4*)Bh;
    uint4* dstp = (uint4*)sB;
    #pragma unroll
    for (int i = 0; i < 8; ++i) dstp[tid + i * 256] = srcp[tid + i * 256];
  }
  {
    int r = tid >> 2, q = tid & 3;
    int n = row0 + r;
    unsigned swz = (unsigned)((r & 7) << 4);
    // x part -> k 0..63 (bytes 0..127 of row)
    float4 xv[4];
    if (n < N_NODES){
      const float4* xr = (const float4*)(x + (size_t)n * 64);
      #pragma unroll
      for (int i = 0; i < 4; ++i) xv[i] = xr[q * 4 + i];
    } else {
      #pragma unroll
      for (int i = 0; i < 4; ++i) xv[i] = make_float4(0.f, 0.f, 0.f, 0.f);
    }
    unsigned pk[8];
    #pragma unroll
    for (int i = 0; i < 4; ++i){
      pk[2 * i]     = pack_bf16(xv[i].x, xv[i].y);
      pk[2 * i + 1] = pack_bf16(xv[i].z, xv[i].w);
    }
    unsigned b0 = (unsigned)(r * 256 + q * 32);
    *(uint4*)(sA + (((b0)      ^ swz) >> 2)) = make_uint4(pk[0], pk[1], pk[2], pk[3]);
    *(uint4*)(sA + (((b0 + 16) ^ swz) >> 2)) = make_uint4(pk[4], pk[5], pk[6], pk[7]);
    // cnt part (already bf16 pairs) -> k 64..127 (bytes 128..255)
    uint4 c0, c1;
    if (n < N_NODES){
      const uint4* cr = (const uint4*)(cb + (size_t)n * 32);
      c0 = cr[q * 2]; c1 = cr[q * 2 + 1];
    } else {
      c0 = make_uint4(0, 0, 0, 0); c1 = c0;
    }
    unsigned b1 = (unsigned)(r * 256 + 128 + q * 32);
    *(uint4*)(sA + (((b1)      ^ swz) >> 2)) = c0;
    *(uint4*)(sA + (((b1 + 16) ^ swz) >> 2)) = c1;
  }
  __syncthreads();

  int wid = tid >> 6, l = tid & 63;
  int c15 = l & 15, kq = l >> 4;
  int arow = wid * 16 + c15;
  f32x4 acc[8];
  #pragma unroll
  for (int nt = 0; nt < 8; ++nt) acc[nt] = (f32x4){0.f, 0.f, 0.f, 0.f};

  #pragma unroll
  for (int kk = 0; kk < 4; ++kk){
    unsigned abyte = (unsigned)(arow * 256 + kk * 64 + kq * 16);
    abyte ^= (unsigned)((arow & 7) << 4);
    short8 af = *(const short8*)((const char*)sA + abyte);
    #pragma unroll
    for (int nt = 0; nt < 8; ++nt){
      short8 bf = *(const short8*)(sB + (size_t)((nt * 4 + kk) * 64 + l) * 4);
      acc[nt] = __builtin_amdgcn_mfma_f32_16x16x32_bf16(af, bf, acc[nt], 0, 0, 0);
    }
  }

  float asv[8], adv[8];
  #pragma unroll
  for (int nt = 0; nt < 8; ++nt){
    asv[nt] = att_s[nt * 16 + c15];
    adv[nt] = att_d[nt * 16 + c15];
  }
  #pragma unroll
  for (int r = 0; r < 4; ++r){
    int row = row0 + wid * 16 + kq * 4 + r;
    bool valid = row < N_NODES;
    #pragma unroll
    for (int h = 0; h < 4; ++h){
      float ps = acc[2 * h][r] * asv[2 * h] + acc[2 * h + 1][r] * asv[2 * h + 1];
      float pd = acc[2 * h][r] * adv[2 * h] + acc[2 * h + 1][r] * adv[2 * h + 1];
      #pragma unroll
      for (int m = 1; m < 16; m <<= 1){
        ps += __shfl_xor(ps, m);
        pd += __shfl_xor(pd, m);
      }
      if (valid && c15 == 0){
        a_src[row * 4 + h] = ps;
        a_dst[row * 4 + h] = pd;
      }
    }
    #pragma unroll
    for (int nt = 0; nt < 8; ++nt){
      float own = acc[nt][r];
      float nb = __shfl_xor(own, 1);
      if (valid && !(c15 & 1))
        xh[(size_t)row * 64 + nt * 8 + (c15 >> 1)] = pack_bf16(own, nb);
    }
  }
}

// ---- fused aggregate (R7 structure): exp (no max), 2-deep prefetch, bias+ELU ----
// wave per node; lane l owns channels (2l, 2l+1) as bf16x2; head h = l>>4.
__global__ __launch_bounds__(256) void k_aggregate(const int* __restrict__ row_dst,
                                                   const unsigned short* __restrict__ lst,
                                                   const float* __restrict__ a_src,
                                                   const float* __restrict__ a_dst,
                                                   const unsigned* __restrict__ xh,
                                                   const float* __restrict__ bias,
                                                   float* __restrict__ out){
  int n = (blockIdx.x * blockDim.x + threadIdx.x) >> 6;
  if (n >= N_NODES) return;
  int l = threadIdx.x & 63;
  int h = l >> 4;
  float ad = a_dst[n * 4 + h];

  float w = __expf(lrelu(a_src[n * 4 + h] + ad));
  unsigned uv = xh[(size_t)n * 64 + l];
  float l0 = w, l1 = 0.f;
  float a0x = w * __uint_as_float(uv << 16);
  float a0y = w * __uint_as_float(uv & 0xFFFF0000u);
  float a1x = 0.f, a1y = 0.f;

  int k0 = row_dst[n], k1 = row_dst[n + 1];
  for (int kb = k0; kb < k1; kb += 64){
    int rem = k1 - kb;
    int nk = rem < 64 ? rem : 64;
    int idx = kb + l;
    int sj = (int)lst[idx < k1 ? idx : k1 - 1];
    int sA = __shfl(sj, 0);
    int sB = __shfl(sj, nk > 1 ? 1 : 0);
    unsigned uA = xh[(size_t)sA * 64 + l]; float aA = a_src[sA * 4 + h];
    unsigned uB = xh[(size_t)sB * 64 + l]; float aB = a_src[sB * 4 + h];
    for (int j = 0; j < nk; j += 2){
      int pA = j + 2 < nk ? j + 2 : nk - 1;
      int pB = j + 3 < nk ? j + 3 : nk - 1;
      int sA2 = __shfl(sj, pA);
      int sB2 = __shfl(sj, pB);
      unsigned uA2 = xh[(size_t)sA2 * 64 + l]; float aA2 = a_src[sA2 * 4 + h];
      unsigned uB2 = xh[(size_t)sB2 * 64 + l]; float aB2 = a_src[sB2 * 4 + h];
      float wA = __expf(lrelu(aA + ad));
      l0 += wA;
      a0x = fmaf(wA, __uint_as_float(uA << 16), a0x);
      a0y = fmaf(wA, __uint_as_float(uA & 0xFFFF0000u), a0y);
      if (j + 1 < nk){
        float wB = __expf(lrelu(aB + ad));
        l1 += wB;
        a1x = fmaf(wB, __uint_as_float(uB << 16), a1x);
        a1y = fmaf(wB, __uint_as_float(uB & 0xFFFF0000u), a1y);
      }
      uA = uA2; aA = aA2; uB = uB2; aB = aB2;
    }
  }
  float lsum = l0 + l1;
  float accx = a0x + a1x;
  float accy = a0y + a1y;
  float2 b = ((const float2*)bias)[l];
  float r0 = accx / lsum + b.x;
  float r1 = accy / lsum + b.y;
  float2 o;
  o.x = r0 > 0.f ? r0 : expm1f(r0);
  o.y = r1 > 0.f ? r1 : expm1f(r1);
  ((float2*)out)[(size_t)n * 64 + l] = o;
}

extern "C" void kernel_launch(void* const* d_in, const int* in_sizes, int n_in,
                              void* d_out, int out_size, void* d_ws, size_t ws_size,
                              hipStream_t stream){
  const float* x     = (const float*)d_in[0];
  const int*   ei    = (const int*)d_in[1];   // [2, E]
  const int*   et    = (const int*)d_in[2];   // [E]
  const float* pe    = (const float*)d_in[3];
  const float* W     = (const float*)d_in[4];
  const float* att_s = (const float*)d_in[5];
  const float* att_d = (const float*)d_in[6];
  const float* bias  = (const float*)d_in[7];
  float* out = (float*)d_out;

  // workspace carve-up (4-byte units)
  int*      btail   = (int*)d_ws;                                  // 2*NB (pad 1024)
  int*      row_dst = btail + 1024;                                // N+1 (pad 8)
  unsigned* Bh      = (unsigned*)(row_dst + N_NODES + 8);          // 8192
  unsigned* cb      = Bh + 8192;                                   // N*32 (bf16-pair counts)
  float*    a_src   = (float*)(cb + (size_t)N_NODES * 32);         // N*4
  float*    a_dst   = a_src + (size_t)N_NODES * 4;                 // N*4
  unsigned* xh      = (unsigned*)(a_dst + (size_t)N_NODES * 4);    // N*64 (bf16x2)
  unsigned* bbuf    = xh + (size_t)N_NODES * 64;                   // 2*NB*BCAP
  unsigned short* lst = (unsigned short*)(bbuf + (size_t)2 * NB * BCAP); // E u16

  const int B = 256;

  hipMemsetAsync(btail, 0, 1024 * sizeof(int), stream);
  k_prep<<<8, B, 0, stream>>>(pe, W, Bh);
  k_histA<<<HIST_BLOCKS, B, 0, stream>>>(ei, et, btail, bbuf);
  k_passB<<<2 * NB, B, 0, stream>>>(bbuf, btail, row_dst, lst, cb);
  k_gemm_mfma<<<ceil_div(N_NODES, GEMM_ROWS), B, 0, stream>>>(x, cb, Bh,
                                                              att_s, att_d,
                                                              a_src, a_dst, xh);
  k_aggregate<<<ceil_div(N_NODES * 64, B), B, 0, stream>>>(row_dst, lst, a_src, a_dst,
                                                           xh, bias, out);
}

// Round 10
// 108.985 us; speedup vs baseline: 1.3744x; 1.0401x over previous
//
#include <hip/hip_runtime.h>
#include <cstdint>
#include <cstddef>

#define N_NODES 50000
#define N_EDGES 800000
#define IN_CH   64
#define OC      128   // HEADS*OUT_CH
#define HEADS   4
#define CH      32    // OUT_CH

#define NB      391        // buckets: 128 nodes each (n>>7); one set for dst, one for src
#define BCAP    2560       // per-bucket capacity (mean 2046, +11 sigma)
#define EPB     2048       // edges per histA block (256 threads x 8)
#define HIST_BLOCKS ((N_EDGES + EPB - 1) / EPB)   // 391

#define SENTINEL N_NODES   // dummy src node: a_src = -1e30 (weight->0), xh row = 0

typedef __attribute__((ext_vector_type(8))) short short8;   // 8 bf16 (4 VGPRs)
typedef __attribute__((ext_vector_type(4))) float f32x4;

static inline int ceil_div(int a, int b){ return (a + b - 1) / b; }

__device__ __forceinline__ float lrelu(float x){ return fmaxf(x, 0.2f * x); }

__device__ __forceinline__ unsigned pack_bf16(float x, float y){
  unsigned ux = __float_as_uint(x), uy = __float_as_uint(y);
  ux += 0x7FFFu + ((ux >> 16) & 1u);
  uy += 0x7FFFu + ((uy >> 16) & 1u);
  return (ux >> 16) | (uy & 0xFFFF0000u);   // low16 = x, high16 = y
}

// ---- K1: block-aggregated scatter into BOTH bucket structures ----
// dst entry: (bd<<23)|(doff<<16)|src ; src entry: (bs<<23)|(soff<<16)|type
__global__ __launch_bounds__(256) void k_histA(const int* __restrict__ ei,
                                               const int* __restrict__ et,
                                               int* __restrict__ btail,
                                               unsigned* __restrict__ bbuf){
  __shared__ int cnt[2 * NB + 2];
  __shared__ int pos[2 * NB + 2];
  int tid = threadIdx.x;
  for (int i = tid; i < 2 * NB + 2; i += 256) cnt[i] = 0;
  __syncthreads();

  int e0 = blockIdx.x * EPB;
  unsigned ed[8], es[8];
  #pragma unroll
  for (int j = 0; j < 8; ++j){
    int e = e0 + j * 256 + tid;
    ed[j] = 0xFFFFFFFFu; es[j] = 0xFFFFFFFFu;
    if (e < N_EDGES){
      int s = ei[e], d = ei[N_EDGES + e], t = et[e];
      ed[j] = ((unsigned)(d >> 7) << 23) | ((unsigned)(d & 127) << 16) | (unsigned)s;
      es[j] = ((unsigned)(s >> 7) << 23) | ((unsigned)(s & 127) << 16) | (unsigned)t;
      atomicAdd(&cnt[ed[j] >> 23], 1);
      atomicAdd(&cnt[NB + (es[j] >> 23)], 1);
    }
  }
  __syncthreads();
  for (int i = tid; i < 2 * NB; i += 256){
    int c = cnt[i];
    pos[i] = c ? atomicAdd(&btail[i], c) : 0;
  }
  __syncthreads();
  #pragma unroll
  for (int j = 0; j < 8; ++j){
    if (ed[j] != 0xFFFFFFFFu){
      int b = ed[j] >> 23;
      int p = atomicAdd(&pos[b], 1);
      if (p < BCAP) bbuf[(size_t)b * BCAP + p] = ed[j];
      int b2 = NB + (es[j] >> 23);
      int p2 = atomicAdd(&pos[b2], 1);
      if (p2 < BCAP) bbuf[(size_t)b2 * BCAP + p2] = es[j];
    }
  }
}

// ---- merged pass B ----
// blocks [0,NB): dst buckets -> row_dst + u16 lst
// blocks [NB,2NB): src buckets -> cb (bf16-pair (node,type) count table, GEMM-ready)
__global__ __launch_bounds__(256) void k_passB(const unsigned* __restrict__ bbuf,
                                               const int* __restrict__ btail,
                                               int* __restrict__ row_dst,
                                               unsigned short* __restrict__ lst,
                                               unsigned* __restrict__ cb){
  int g = blockIdx.x, tid = threadIdx.x;
  if (g < NB){
    __shared__ int cnt[128], sc[128], cur[128], red[256];
    __shared__ int sbase;
    int d0 = g << 7;
    int nn = min(128, N_NODES - d0);
    int cnt_b = min(btail[g], BCAP);
    // bucket base = sum of previous dst-bucket sizes
    int part = 0;
    for (int q = tid; q < g; q += 256) part += min(btail[q], BCAP);
    red[tid] = part; __syncthreads();
    for (int off = 128; off > 0; off >>= 1){
      if (tid < off) red[tid] += red[tid + off];
      __syncthreads();
    }
    if (tid == 0) sbase = red[0];
    if (tid < 128) cnt[tid] = 0;
    __syncthreads();
    int base0 = sbase;
    for (int i = tid; i < cnt_b; i += 256)
      atomicAdd(&cnt[(bbuf[(size_t)g * BCAP + i] >> 16) & 127], 1);
    __syncthreads();
    if (tid < 128) sc[tid] = cnt[tid];
    __syncthreads();
    for (int off = 1; off < 128; off <<= 1){
      int t = (tid < 128 && tid >= off) ? sc[tid - off] : 0;
      __syncthreads();
      if (tid < 128) sc[tid] += t;
      __syncthreads();
    }
    if (tid < nn){
      int ex = sc[tid] - cnt[tid];
      cur[tid] = ex;
      row_dst[d0 + tid] = base0 + ex;
    }
    if (g == NB - 1 && tid == 0) row_dst[N_NODES] = base0 + cnt_b;
    __syncthreads();
    for (int i = tid; i < cnt_b; i += 256){
      unsigned e = bbuf[(size_t)g * BCAP + i];
      int p = atomicAdd(&cur[(e >> 16) & 127], 1);
      lst[base0 + p] = (unsigned short)(e & 0xFFFFu);
    }
  } else {
    __shared__ unsigned hist[128 * 16];   // u8-packed per-node type counts, 8 KB
    int n0 = (g - NB) << 7;
    int nn = min(128, N_NODES - n0);
    for (int i = tid; i < 2048; i += 256) hist[i] = 0;
    __syncthreads();
    int cnt_b = min(btail[g], BCAP);
    for (int i = tid; i < cnt_b; i += 256){
      unsigned e = bbuf[(size_t)g * BCAP + i];
      unsigned t = e & 63u;
      atomicAdd(&hist[((e >> 16) & 127) * 16 + (t >> 2)], 1u << (8 * (t & 3)));
    }
    __syncthreads();
    for (int o = tid; o < 4096; o += 256){
      int i = o >> 5, j = o & 31;
      if (i < nn){
        unsigned w = hist[i * 16 + (j >> 1)];
        unsigned sh = 16 * (j & 1);
        cb[(size_t)(n0 + i) * 32 + j] =
          pack_bf16((float)((w >> sh) & 0xFFu), (float)((w >> (sh + 8)) & 0xFFu));
      }
    }
  }
}

// ---- k_prep (8 blocks): Bh = bf16 frag-packed [W ; pe@W], 16-col slice per block ----
// block 0 additionally does all small inits (btail zero, sentinels, lst pad).
__global__ __launch_bounds__(256) void k_prep(const float* __restrict__ pe,
                                              const float* __restrict__ W,
                                              unsigned* __restrict__ Bh,
                                              int* __restrict__ btail,
                                              float* __restrict__ a_src,
                                              unsigned* __restrict__ xh,
                                              unsigned short* __restrict__ lst){
  __shared__ float sPe[64 * 64];    // 16 KB
  __shared__ float sW64[64 * 16];   // [k][j], 4 KB
  __shared__ float sPeW[64 * 16];   // [t][j], 4 KB
  int tid = threadIdx.x;
  int nt = blockIdx.x;
  int n0 = nt * 16;
  if (nt == 0){
    for (int i = tid; i < 1024; i += 256) btail[i] = 0;
    if (tid < 64) xh[(size_t)SENTINEL * 64 + tid] = 0;        // zero sentinel message row
    if (tid < 4)  a_src[SENTINEL * 4 + tid] = -1e30f;         // weight -> exp(-inf) = 0
    if (tid < 8)  lst[N_EDGES + tid] = (unsigned short)SENTINEL;
  }
  for (int i = tid; i < 1024; i += 256)
    ((float4*)sPe)[i] = ((const float4*)pe)[i];
  for (int i = tid; i < 1024; i += 256){
    int k = i >> 4, j = i & 15;
    sW64[i] = W[k * 128 + n0 + j];
  }
  __syncthreads();
  for (int i = tid; i < 1024; i += 256){
    int t = i >> 4, j = i & 15;
    float a = 0.f;
    #pragma unroll
    for (int k = 0; k < 64; ++k) a += sPe[t * 64 + k] * sW64[k * 16 + j];
    sPeW[i] = a;
  }
  __syncthreads();
  for (int m = tid; m < 1024; m += 256){
    int j2 = m & 3, l = (m >> 2) & 63, kk = m >> 8;
    int k = kk * 32 + (l >> 4) * 8 + 2 * j2;   // even, pairs never straddle 64
    int jl = l & 15;
    float v0, v1;
    if (k < 64){ v0 = sW64[k * 16 + jl]; v1 = sW64[(k + 1) * 16 + jl]; }
    else       { v0 = sPeW[(k - 64) * 16 + jl]; v1 = sPeW[(k - 63) * 16 + jl]; }
    Bh[nt * 1024 + m] = pack_bf16(v0, v1);
  }
}

// ---- MFMA GEMM: xl = [x | cnt] @ [W ; peW], 64 rows/block, 4 waves ----
#define GEMM_ROWS 64
__global__ __launch_bounds__(256) void k_gemm_mfma(const float* __restrict__ x,
                                                   const unsigned* __restrict__ cb,
                                                   const unsigned* __restrict__ Bh,
                                                   const float* __restrict__ att_s,
                                                   const float* __restrict__ att_d,
                                                   float* __restrict__ a_src,
                                                   float* __restrict__ a_dst,
                                                   unsigned* __restrict__ xh){
  __shared__ unsigned sA[4096];   // 64 rows x 128 k bf16, XOR-swizzled, 16 KB
  __shared__ unsigned sB[8192];   // frag-packed B, 32 KB
  int tid = threadIdx.x;
  int row0 = blockIdx.x * GEMM_ROWS;

  {
    const uint4* srcp = (const uint4*)Bh;
    uint4* dstp = (uint4*)sB;
    #pragma unroll
    for (int i = 0; i < 8; ++i) dstp[tid + i * 256] = srcp[tid + i * 256];
  }
  {
    int r = tid >> 2, q = tid & 3;
    int n = row0 + r;
    unsigned swz = (unsigned)((r & 7) << 4);
    // x part -> k 0..63 (bytes 0..127 of row)
    float4 xv[4];
    if (n < N_NODES){
      const float4* xr = (const float4*)(x + (size_t)n * 64);
      #pragma unroll
      for (int i = 0; i < 4; ++i) xv[i] = xr[q * 4 + i];
    } else {
      #pragma unroll
      for (int i = 0; i < 4; ++i) xv[i] = make_float4(0.f, 0.f, 0.f, 0.f);
    }
    unsigned pk[8];
    #pragma unroll
    for (int i = 0; i < 4; ++i){
      pk[2 * i]     = pack_bf16(xv[i].x, xv[i].y);
      pk[2 * i + 1] = pack_bf16(xv[i].z, xv[i].w);
    }
    unsigned b0 = (unsigned)(r * 256 + q * 32);
    *(uint4*)(sA + (((b0)      ^ swz) >> 2)) = make_uint4(pk[0], pk[1], pk[2], pk[3]);
    *(uint4*)(sA + (((b0 + 16) ^ swz) >> 2)) = make_uint4(pk[4], pk[5], pk[6], pk[7]);
    // cnt part (already bf16 pairs) -> k 64..127 (bytes 128..255)
    uint4 c0, c1;
    if (n < N_NODES){
      const uint4* cr = (const uint4*)(cb + (size_t)n * 32);
      c0 = cr[q * 2]; c1 = cr[q * 2 + 1];
    } else {
      c0 = make_uint4(0, 0, 0, 0); c1 = c0;
    }
    unsigned b1 = (unsigned)(r * 256 + 128 + q * 32);
    *(uint4*)(sA + (((b1)      ^ swz) >> 2)) = c0;
    *(uint4*)(sA + (((b1 + 16) ^ swz) >> 2)) = c1;
  }
  __syncthreads();

  int wid = tid >> 6, l = tid & 63;
  int c15 = l & 15, kq = l >> 4;
  int arow = wid * 16 + c15;
  f32x4 acc[8];
  #pragma unroll
  for (int nt = 0; nt < 8; ++nt) acc[nt] = (f32x4){0.f, 0.f, 0.f, 0.f};

  #pragma unroll
  for (int kk = 0; kk < 4; ++kk){
    unsigned abyte = (unsigned)(arow * 256 + kk * 64 + kq * 16);
    abyte ^= (unsigned)((arow & 7) << 4);
    short8 af = *(const short8*)((const char*)sA + abyte);
    #pragma unroll
    for (int nt = 0; nt < 8; ++nt){
      short8 bf = *(const short8*)(sB + (size_t)((nt * 4 + kk) * 64 + l) * 4);
      acc[nt] = __builtin_amdgcn_mfma_f32_16x16x32_bf16(af, bf, acc[nt], 0, 0, 0);
    }
  }

  float asv[8], adv[8];
  #pragma unroll
  for (int nt = 0; nt < 8; ++nt){
    asv[nt] = att_s[nt * 16 + c15];
    adv[nt] = att_d[nt * 16 + c15];
  }
  #pragma unroll
  for (int r = 0; r < 4; ++r){
    int row = row0 + wid * 16 + kq * 4 + r;
    bool valid = row < N_NODES;
    #pragma unroll
    for (int h = 0; h < 4; ++h){
      float ps = acc[2 * h][r] * asv[2 * h] + acc[2 * h + 1][r] * asv[2 * h + 1];
      float pd = acc[2 * h][r] * adv[2 * h] + acc[2 * h + 1][r] * adv[2 * h + 1];
      #pragma unroll
      for (int m = 1; m < 16; m <<= 1){
        ps += __shfl_xor(ps, m);
        pd += __shfl_xor(pd, m);
      }
      if (valid && c15 == 0){
        a_src[row * 4 + h] = ps;
        a_dst[row * 4 + h] = pd;
      }
    }
    #pragma unroll
    for (int nt = 0; nt < 8; ++nt){
      float own = acc[nt][r];
      float nb = __shfl_xor(own, 1);
      if (valid && !(c15 & 1))
        xh[(size_t)row * 64 + nt * 8 + (c15 >> 1)] = pack_bf16(own, nb);
    }
  }
}

// ---- fused aggregate: uniform lst loads, 4-deep prefetch, sentinel guards ----
// wave per node; lane l owns channels (2l, 2l+1) as bf16x2; head h = l>>4.
__global__ __launch_bounds__(256) void k_aggregate(const int* __restrict__ row_dst,
                                                   const unsigned short* __restrict__ lst,
                                                   const float* __restrict__ a_src,
                                                   const float* __restrict__ a_dst,
                                                   const unsigned* __restrict__ xh,
                                                   const float* __restrict__ bias,
                                                   float* __restrict__ out){
  int n = (blockIdx.x * blockDim.x + threadIdx.x) >> 6;
  if (n >= N_NODES) return;
  int l = threadIdx.x & 63;
  int h = l >> 4;
  float ad = a_dst[n * 4 + h];

  // self loop
  float w = __expf(lrelu(a_src[n * 4 + h] + ad));
  unsigned uv = xh[(size_t)n * 64 + l];
  float l0 = w, l1 = 0.f, l2 = 0.f, l3 = 0.f;
  float a0x = w * __uint_as_float(uv << 16);
  float a0y = w * __uint_as_float(uv & 0xFFFF0000u);
  float a1x = 0.f, a1y = 0.f, a2x = 0.f, a2y = 0.f, a3x = 0.f, a3y = 0.f;

  int k0 = row_dst[n], k1 = row_dst[n + 1];

  // prologue: edges k0..k0+3 (reads beyond k1 hit neighbor rows / sentinel pad — guarded at use)
  int sA = (int)lst[k0], sB = (int)lst[k0 + 1], sC = (int)lst[k0 + 2], sD = (int)lst[k0 + 3];
  unsigned uA = xh[(size_t)sA * 64 + l]; float bA = a_src[sA * 4 + h];
  unsigned uB = xh[(size_t)sB * 64 + l]; float bB = a_src[sB * 4 + h];
  unsigned uC = xh[(size_t)sC * 64 + l]; float bC = a_src[sC * 4 + h];
  unsigned uD = xh[(size_t)sD * 64 + l]; float bD = a_src[sD * 4 + h];

  for (int j = k0; j < k1; j += 4){
    // prefetch edges j+4..j+7
    int nsA = (int)lst[j + 4], nsB = (int)lst[j + 5];
    int nsC = (int)lst[j + 6], nsD = (int)lst[j + 7];
    unsigned nuA = xh[(size_t)nsA * 64 + l]; float nbA = a_src[nsA * 4 + h];
    unsigned nuB = xh[(size_t)nsB * 64 + l]; float nbB = a_src[nsB * 4 + h];
    unsigned nuC = xh[(size_t)nsC * 64 + l]; float nbC = a_src[nsC * 4 + h];
    unsigned nuD = xh[(size_t)nsD * 64 + l]; float nbD = a_src[nsD * 4 + h];
    // process edges j..j+3 (A is always in-range; B/C/D wave-uniform guards)
    float wA = __expf(lrelu(bA + ad));
    l0 += wA;
    a0x = fmaf(wA, __uint_as_float(uA << 16), a0x);
    a0y = fmaf(wA, __uint_as_float(uA & 0xFFFF0000u), a0y);
    float wB = (j + 1 < k1) ? __expf(lrelu(bB + ad)) : 0.f;
    l1 += wB;
    a1x = fmaf(wB, __uint_as_float(uB << 16), a1x);
    a1y = fmaf(wB, __uint_as_float(uB & 0xFFFF0000u), a1y);
    float wC = (j + 2 < k1) ? __expf(lrelu(bC + ad)) : 0.f;
    l2 += wC;
    a2x = fmaf(wC, __uint_as_float(uC << 16), a2x);
    a2y = fmaf(wC, __uint_as_float(uC & 0xFFFF0000u), a2y);
    float wD = (j + 3 < k1) ? __expf(lrelu(bD + ad)) : 0.f;
    l3 += wD;
    a3x = fmaf(wD, __uint_as_float(uD << 16), a3x);
    a3y = fmaf(wD, __uint_as_float(uD & 0xFFFF0000u), a3y);
    // rotate
    sA = nsA; uA = nuA; bA = nbA;
    sB = nsB; uB = nuB; bB = nbB;
    sC = nsC; uC = nuC; bC = nbC;
    sD = nsD; uD = nuD; bD = nbD;
  }
  float lsum = (l0 + l1) + (l2 + l3);
  float accx = (a0x + a1x) + (a2x + a3x);
  float accy = (a0y + a1y) + (a2y + a3y);
  float2 b = ((const float2*)bias)[l];
  float r0 = accx / lsum + b.x;
  float r1 = accy / lsum + b.y;
  float2 o;
  o.x = r0 > 0.f ? r0 : expm1f(r0);
  o.y = r1 > 0.f ? r1 : expm1f(r1);
  ((float2*)out)[(size_t)n * 64 + l] = o;
}

extern "C" void kernel_launch(void* const* d_in, const int* in_sizes, int n_in,
                              void* d_out, int out_size, void* d_ws, size_t ws_size,
                              hipStream_t stream){
  const float* x     = (const float*)d_in[0];
  const int*   ei    = (const int*)d_in[1];   // [2, E]
  const int*   et    = (const int*)d_in[2];   // [E]
  const float* pe    = (const float*)d_in[3];
  const float* W     = (const float*)d_in[4];
  const float* att_s = (const float*)d_in[5];
  const float* att_d = (const float*)d_in[6];
  const float* bias  = (const float*)d_in[7];
  float* out = (float*)d_out;

  // workspace carve-up (4-byte units)
  int*      btail   = (int*)d_ws;                                  // 2*NB (pad 1024)
  int*      row_dst = btail + 1024;                                // N+1 (pad 8)
  unsigned* Bh      = (unsigned*)(row_dst + N_NODES + 8);          // 8192
  unsigned* cb      = Bh + 8192;                                   // N*32 (bf16-pair counts)
  float*    a_src   = (float*)(cb + (size_t)N_NODES * 32);         // (N+1)*4 (sentinel row)
  float*    a_dst   = a_src + (size_t)(N_NODES + 1) * 4;           // N*4
  unsigned* xh      = (unsigned*)(a_dst + (size_t)N_NODES * 4);    // (N+1)*64 (sentinel row)
  unsigned* bbuf    = xh + (size_t)(N_NODES + 1) * 64;             // 2*NB*BCAP
  unsigned short* lst = (unsigned short*)(bbuf + (size_t)2 * NB * BCAP); // E+8 u16

  const int B = 256;

  k_prep<<<8, B, 0, stream>>>(pe, W, Bh, btail, a_src, xh, lst);
  k_histA<<<HIST_BLOCKS, B, 0, stream>>>(ei, et, btail, bbuf);
  k_passB<<<2 * NB, B, 0, stream>>>(bbuf, btail, row_dst, lst, cb);
  k_gemm_mfma<<<ceil_div(N_NODES, GEMM_ROWS), B, 0, stream>>>(x, cb, Bh,
                                                              att_s, att_d,
                                                              a_src, a_dst, xh);
  k_aggregate<<<ceil_div(N_NODES * 64, B), B, 0, stream>>>(row_dst, lst, a_src, a_dst,
                                                           xh, bias, out);
}